// Round 5
// baseline (136.338 us; speedup 1.0000x reference)
//
#include <hip/hip_runtime.h>

// Problem constants
#define BATCH  4
#define SEQL   2048
#define DMODEL 1024
#define CT     64            // chunk length
#define NCH    (SEQL / CT)   // 32 chunks

// ---------------------------------------------------------------------------
// ONE fused kernel. 256 blocks x 256 threads, block = (b, 16-channel group).
// ws is never touched -> hin lives in LDS, tables in regs/LDS, 1 launch.
//
// Phase T: fp64 log-depth doubling (proven from round-4 KA):
//   Vd[d] = A^d B, Wd[d] = B^T A^d (d<=64), M = A^64.
//   kvext[127]: kvext[63+d] = B^T A^d B (d=0..63), zeros for d<0.
//
// Chunk loop (j = 0..31), double-buffered x tile xsT[buf][ch][sigma]:
//   OUTPUT: wave w owns taus [16w,16w+16) (i compile-time); lane = (ch=l&15,
//     part=l>>4) covers sigma quarter [16part,16part+16) (k compile-time).
//     kv register window kvs[31]: kvs[i-k+15] = kvext[63 + 16(w-part)+(i-k)]
//     = kv[tau-ss], zero-padded for acausal terms -> NO masks, all indices
//     static. yv[i] += W[tau].h_in partial (m in [4part,4part+4)).
//     2-round __shfl_xor butterfly (^16,^32) sums the 4 part-partials;
//     switch(part) stores 4 rows each (64B line-complete).
//   SCAN: thread (chS=t>>4, m=t&15): c = sum_sigma P[sigma][m] x[sigma][chS]
//     (b128 from LDS), s = Apow*s + c via proven 16-lane shfl matvec.
//     s_{j-1} kept in sLDS[16][17] = the in-LDS hin (1KB, never global).
// Traffic: x 32MB read once + y 32MB write = 64MB total.
// ---------------------------------------------------------------------------
__global__ __launch_bounds__(256, 1) void fused_all(const float* __restrict__ x,
                                                    const float* __restrict__ Ain,
                                                    const float* __restrict__ Bvin,
                                                    float* __restrict__ y) {
    __shared__ double Mb[256], Mt[256];          // A^(2^k), scratch
    __shared__ double Vd[64][16];                // v_d = A^d B
    __shared__ double Wd[65][16];                // w_d = B^T A^d
    __shared__ double bd[16];
    __shared__ __align__(16) float xsT[2][16][68];  // [buf][ch][sigma], padded
    __shared__ float sLDS[16][17];               // s_{j-1} per (ch, m) = hin
    __shared__ float kvLDS[128];                 // kvext

    const int t   = threadIdx.x;
    const int blk = blockIdx.x;          // 256 = BATCH * 64 groups
    const int b   = blk >> 6;
    const int g   = blk & 63;
    const int d0  = g * 16;

    const int l    = t & 63;             // lane
    const int wv   = t >> 6;             // wave = tau block TT
    const int part = l >> 4;             // sigma quarter (output role)
    const int chT  = l & 15;             // channel (output role)
    const int chS  = t >> 4;             // channel (scan role)
    const int m    = t & 15;             // state component (scan role)
    const int sigma = t >> 2;            // stage role: row
    const int c4    = t & 3;             // stage role: float4 col
    const int laneBase = l & 48;

    // ---------------- Phase T: tables via fp64 doubling (proven) ----------
    Mb[t] = (double)Ain[t];
    if (t < 16) {
        bd[t]    = (double)Bvin[t];
        Vd[0][t] = (double)Bvin[t];
        Wd[0][t] = (double)Bvin[t];
    }
    __syncthreads();

    #pragma unroll
    for (int k = 0; k < 6; ++k) {        // Mb = A^(2^k) entering round k
        const int cnt = 1 << k;
        const int mm  = t & 15;
        for (int dd = t >> 4; dd < cnt; dd += 16) {
            double av = 0.0, aw = 0.0;
            #pragma unroll
            for (int q = 0; q < 16; ++q) {
                av += Mb[mm * 16 + q] * Vd[dd][q];
                aw += Wd[dd][q] * Mb[q * 16 + mm];
            }
            Vd[dd + cnt][mm] = av;
            Wd[dd + cnt][mm] = aw;
        }
        __syncthreads();
        {
            const int i = t >> 4, jj = t & 15;
            double acc = 0.0;
            #pragma unroll
            for (int q = 0; q < 16; ++q) acc += Mb[i * 16 + q] * Mb[q * 16 + jj];
            Mt[t] = acc;
            if (k == 5 && t < 16) {
                double aw = 0.0;
                #pragma unroll
                for (int q = 0; q < 16; ++q) aw += Wd[32][q] * Mb[q * 16 + t];
                Wd[64][t] = aw;
            }
        }
        __syncthreads();
        Mb[t] = Mt[t];
        __syncthreads();
    }
    // Mb = A^64; Vd[0..63], Wd[0..64] complete.

    // kvext + sLDS init + stage chunk 0, all before one barrier
    if (t < 64) {
        double kd = 0.0;
        #pragma unroll
        for (int q = 0; q < 16; ++q) kd += bd[q] * Vd[t][q];
        kvLDS[63 + t] = (float)kd;
    } else if (t < 127) {
        kvLDS[t - 64] = 0.0f;            // zero lags < 0  (indices 0..62)
    } else {
        kvLDS[127] = 0.0f;
    }
    sLDS[chS][m] = 0.0f;                 // s_{-1} = 0

    const float* xbase = x + (size_t)(b * SEQL) * DMODEL + d0 + 4 * c4;
    {
        float4 cur = *(const float4*)(xbase + (size_t)sigma * DMODEL);
        xsT[0][4 * c4 + 0][sigma] = cur.x;
        xsT[0][4 * c4 + 1][sigma] = cur.y;
        xsT[0][4 * c4 + 2][sigma] = cur.z;
        xsT[0][4 * c4 + 3][sigma] = cur.w;
    }
    __syncthreads();

    // ---------------- per-thread register tables ----------------
    float Preg[64];                      // P[sigma][m] = Vd[63-sigma][m]
    #pragma unroll
    for (int sg = 0; sg < 64; ++sg) Preg[sg] = (float)Vd[63 - sg][m];

    float Arow[16];                      // A^64 row m
    #pragma unroll
    for (int k = 0; k < 16; ++k) Arow[k] = (float)Mb[m * 16 + k];

    float kvs[31];                       // kv window: kvs[i-k+15] = kv[tau-ss]
    {
        const int kvbase = 48 + 16 * (wv - part);   // in [0, 96]
        #pragma unroll
        for (int u = 0; u < 31; ++u) kvs[u] = kvLDS[kvbase + u];
    }

    float Wreg[16][4];                   // W[16wv+i][4part+mm] = Wd[tau+1][.]
    #pragma unroll
    for (int i = 0; i < 16; ++i)
        #pragma unroll
        for (int mm = 0; mm < 4; ++mm)
            Wreg[i][mm] = (float)Wd[16 * wv + i + 1][4 * part + mm];

    // ---------------- chunk loop ----------------
    float s = 0.0f;
    int buf = 0;
    for (int j = 0; j < NCH; ++j) {
        // issue next-chunk global load early (consumed after the barrier)
        float4 nxt;
        if (j + 1 < NCH)
            nxt = *(const float4*)(xbase + (size_t)((j + 1) * CT + sigma) * DMODEL);

        // ---- OUTPUT role: triangle partial over sigma in [16part,16part+16)
        float xcol[16];
        #pragma unroll
        for (int k4 = 0; k4 < 4; ++k4) {
            const float4 v = *(const float4*)(&xsT[buf][chT][16 * part + 4 * k4]);
            xcol[4 * k4 + 0] = v.x; xcol[4 * k4 + 1] = v.y;
            xcol[4 * k4 + 2] = v.z; xcol[4 * k4 + 3] = v.w;
        }
        float yv[16];
        #pragma unroll
        for (int i = 0; i < 16; ++i) yv[i] = 0.0f;
        #pragma unroll
        for (int k = 0; k < 16; ++k)
            #pragma unroll
            for (int i = 0; i < 16; ++i)
                yv[i] = fmaf(kvs[i - k + 15], xcol[k], yv[i]);

        // W[tau].h_in partial (m in [4part, 4part+4)); sLDS holds s_{j-1}
        float h4[4];
        #pragma unroll
        for (int mm = 0; mm < 4; ++mm) h4[mm] = sLDS[chT][4 * part + mm];
        #pragma unroll
        for (int i = 0; i < 16; ++i)
            #pragma unroll
            for (int mm = 0; mm < 4; ++mm)
                yv[i] = fmaf(Wreg[i][mm], h4[mm], yv[i]);

        // butterfly-sum the 4 part-partials (lanes ^16, ^32)
        #pragma unroll
        for (int i = 0; i < 16; ++i) {
            yv[i] += __shfl_xor(yv[i], 16, 64);
            yv[i] += __shfl_xor(yv[i], 32, 64);
        }

        // store: lane (ch, part) writes taus 16wv + 4part + (0..3)
        {
            float* yp = y + ((size_t)(b * SEQL + j * CT + 16 * wv)) * DMODEL + d0 + chT;
            switch (part) {
                case 0:
                    yp[0 * (size_t)DMODEL]  = yv[0];  yp[1 * (size_t)DMODEL]  = yv[1];
                    yp[2 * (size_t)DMODEL]  = yv[2];  yp[3 * (size_t)DMODEL]  = yv[3];
                    break;
                case 1:
                    yp[4 * (size_t)DMODEL]  = yv[4];  yp[5 * (size_t)DMODEL]  = yv[5];
                    yp[6 * (size_t)DMODEL]  = yv[6];  yp[7 * (size_t)DMODEL]  = yv[7];
                    break;
                case 2:
                    yp[8 * (size_t)DMODEL]  = yv[8];  yp[9 * (size_t)DMODEL]  = yv[9];
                    yp[10 * (size_t)DMODEL] = yv[10]; yp[11 * (size_t)DMODEL] = yv[11];
                    break;
                default:
                    yp[12 * (size_t)DMODEL] = yv[12]; yp[13 * (size_t)DMODEL] = yv[13];
                    yp[14 * (size_t)DMODEL] = yv[14]; yp[15 * (size_t)DMODEL] = yv[15];
                    break;
            }
        }

        // ---- SCAN role: c(chS,m) then s_j = A^64 s_{j-1} + c
        float c = 0.0f;
        #pragma unroll
        for (int sg4 = 0; sg4 < 16; ++sg4) {
            const float4 v = *(const float4*)(&xsT[buf][chS][4 * sg4]);
            c = fmaf(Preg[4 * sg4 + 0], v.x, c);
            c = fmaf(Preg[4 * sg4 + 1], v.y, c);
            c = fmaf(Preg[4 * sg4 + 2], v.z, c);
            c = fmaf(Preg[4 * sg4 + 3], v.w, c);
        }
        float acc = c;
        #pragma unroll
        for (int k = 0; k < 16; ++k)
            acc = fmaf(Arow[k], __shfl(s, laneBase + k, 64), acc);

        __syncthreads();                 // all sLDS/xsT reads of chunk j done

        s = acc;
        sLDS[chS][m] = s;                // s_j -> hin for chunk j+1
        if (j + 1 < NCH) {               // stage next tile into other buffer
            xsT[buf ^ 1][4 * c4 + 0][sigma] = nxt.x;
            xsT[buf ^ 1][4 * c4 + 1][sigma] = nxt.y;
            xsT[buf ^ 1][4 * c4 + 2][sigma] = nxt.z;
            xsT[buf ^ 1][4 * c4 + 3][sigma] = nxt.w;
        }
        __syncthreads();                 // tile + sLDS ready for chunk j+1
        buf ^= 1;
    }
}

// ---------------------------------------------------------------------------
extern "C" void kernel_launch(void* const* d_in, const int* in_sizes, int n_in,
                              void* d_out, int out_size, void* d_ws, size_t ws_size,
                              hipStream_t stream) {
    (void)in_sizes; (void)n_in; (void)out_size; (void)d_ws; (void)ws_size;
    const float* x  = (const float*)d_in[0];
    const float* A  = (const float*)d_in[1];
    const float* Bv = (const float*)d_in[2];
    float* out = (float*)d_out;

    fused_all<<<256, 256, 0, stream>>>(x, A, Bv, out);
}

// Round 6
// 118.189 us; speedup vs baseline: 1.1536x; 1.1536x over previous
//
#include <hip/hip_runtime.h>

// Problem constants
#define BATCH  4
#define SEQL   2048
#define DMODEL 1024
#define CT     64            // chunk length
#define NCH    (SEQL / CT)   // 32 chunks

// ws layout (float offsets). ws_size = 256 MiB, we use ~8.5 MiB.
#define WS_W     1024        // W[tau][m] = (B^T A^(tau+1))[m]  : 64*16
#define WS_KV    2048        // kvext[127]; kvext[63+d] = B^T A^d B
#define WS_HIN   4096        // hin[b][j][d][m] = s_{j-1}       : B*NCH*D*16

// ---------------------------------------------------------------------------
// KA v2: fused tables + chunk-state + carry scan. 256 blocks x 256 threads.
// Block = (b, 16-channel group). Thread = (ch = t>>4, m = t&15).
//
// Phase T (proven R4 code): fp64 log-depth doubling -> Vd[d]=A^d B,
//   Wd[d]=B^T A^d, M=A^64; writes W/kv tables to ws for K3.
// Phase S changes vs R4 (latency chain was ~2000 cyc/chunk at 1 wave/SIMD):
//   - double-buffered xsT[2][16][68], ONE barrier per chunk (was 2)
//   - 2-chunk-deep global prefetch (load j+2 while computing j)
//   - c-accumulation split into 4 independent FMA chains (was 1x64 serial)
//   - shfl-matvec split into 2 independent chains (was 1x16 serial)
// ---------------------------------------------------------------------------
__global__ __launch_bounds__(256) void ka_tables_scan(const float* __restrict__ x,
                                                      const float* __restrict__ Ain,
                                                      const float* __restrict__ Bvin,
                                                      float* __restrict__ ws) {
    __shared__ double M[256], Mt[256];     // A^(2^k), scratch
    __shared__ double Vd[64][16];          // v_d = A^d B
    __shared__ double Wd[65][16];          // w_d = B^T A^d
    __shared__ double bd[16];
    __shared__ float  Pl[64][16];          // P[sigma][m] = v_{63-sigma}[m]
    __shared__ float  Ap[256];             // A^64 fp32
    __shared__ __align__(16) float xsT[2][16][68];  // dbuf transposed tile

    const int t   = threadIdx.x;
    const int blk = blockIdx.x;            // 256 blocks
    const int b   = blk >> 6;
    const int g   = blk & 63;
    const int d0  = g * 16;

    // ---------------- Phase T: tables via fp64 doubling (proven) ----------
    M[t] = (double)Ain[t];
    if (t < 16) {
        bd[t]    = (double)Bvin[t];
        Vd[0][t] = (double)Bvin[t];        // v_0 = B
        Wd[0][t] = (double)Bvin[t];        // w_0 = B^T
    }
    __syncthreads();

    #pragma unroll
    for (int k = 0; k < 6; ++k) {          // M = A^(2^k) entering round k
        const int cnt = 1 << k;
        const int mm  = t & 15;
        for (int dd = t >> 4; dd < cnt; dd += 16) {
            double av = 0.0, aw = 0.0;
            #pragma unroll
            for (int l = 0; l < 16; ++l) {
                av += M[mm * 16 + l] * Vd[dd][l];
                aw += Wd[dd][l] * M[l * 16 + mm];
            }
            Vd[dd + cnt][mm] = av;
            Wd[dd + cnt][mm] = aw;
        }
        __syncthreads();
        {
            const int i = t >> 4, jj = t & 15;
            double acc = 0.0;
            #pragma unroll
            for (int l = 0; l < 16; ++l) acc += M[i * 16 + l] * M[l * 16 + jj];
            Mt[t] = acc;
            if (k == 5 && t < 16) {
                double aw = 0.0;
                #pragma unroll
                for (int l = 0; l < 16; ++l) aw += Wd[32][l] * M[l * 16 + t];
                Wd[64][t] = aw;
            }
        }
        __syncthreads();
        M[t] = Mt[t];
        __syncthreads();
    }
    // M = A^64; Vd[0..63], Wd[0..64] complete.

    // fp32 tables + global table writes for K3 (all blocks write same data)
    Ap[t] = (float)M[t];
    for (int e = t; e < 1024; e += 256) {
        const int r = e >> 4, mm = e & 15;
        Pl[r][mm] = (float)Vd[63 - r][mm];            // P[sigma][m]
        ws[WS_W + e] = (float)Wd[r + 1][mm];          // W[tau][m]
    }
    if (t < 64) {                                      // kv[d] = B^T A^d B
        double kd = 0.0;
        #pragma unroll
        for (int mm = 0; mm < 16; ++mm) kd += bd[mm] * Vd[t][mm];
        ws[WS_KV + 63 + t] = (float)kd;
    }

    // ---------------- Phase S ----------------
    const int ch = t >> 4;                 // channel within group
    const int m  = t & 15;                 // state component
    const int laneBase = t & 48;
    const int sigma = t >> 2;              // stage role: row
    const int c4    = t & 3;               // stage role: float4 col

    const float* xb2 = x + (size_t)(b * SEQL) * DMODEL + d0 + 4 * c4;
    float* hin = ws + WS_HIN;

    // prologue: tile 0 -> LDS buf0; tile 1 -> regs (cur); then one barrier
    {
        float4 v0 = *(const float4*)(xb2 + (size_t)sigma * DMODEL);
        xsT[0][4 * c4 + 0][sigma] = v0.x;
        xsT[0][4 * c4 + 1][sigma] = v0.y;
        xsT[0][4 * c4 + 2][sigma] = v0.z;
        xsT[0][4 * c4 + 3][sigma] = v0.w;
    }
    float4 cur = *(const float4*)(xb2 + (size_t)(CT + sigma) * DMODEL);
    __syncthreads();                       // covers Pl/Ap writes + tile 0

    float Preg[64];                        // P[.][m] column in registers
    #pragma unroll
    for (int sg = 0; sg < 64; ++sg) Preg[sg] = Pl[sg][m];

    float Arow[16];
    #pragma unroll
    for (int k = 0; k < 16; ++k) Arow[k] = Ap[m * 16 + k];

    float s = 0.0f;
    int buf = 0;
    for (int j = 0; j < NCH; ++j) {
        // 2-deep prefetch: issue load for tile j+2 (consumed next iter)
        float4 nxt = cur;
        if (j + 2 < NCH)
            nxt = *(const float4*)(xb2 + (size_t)((j + 2) * CT + sigma) * DMODEL);

        // stage tile j+1 (in cur) into the other buffer — concurrent with
        // this iter's reads of xsT[buf] (different buffer, no hazard)
        if (j + 1 < NCH) {
            xsT[buf ^ 1][4 * c4 + 0][sigma] = cur.x;
            xsT[buf ^ 1][4 * c4 + 1][sigma] = cur.y;
            xsT[buf ^ 1][4 * c4 + 2][sigma] = cur.z;
            xsT[buf ^ 1][4 * c4 + 3][sigma] = cur.w;
        }

        // c(ch,m) = sum_sigma P[sigma][m] x[sigma][ch] — 4 independent chains
        float a0 = 0.0f, a1 = 0.0f, a2 = 0.0f, a3 = 0.0f;
        #pragma unroll
        for (int r = 0; r < 4; ++r) {
            const int o = 16 * r;
            const float4 q0 = *(const float4*)(&xsT[buf][ch][o + 0]);
            const float4 q1 = *(const float4*)(&xsT[buf][ch][o + 4]);
            const float4 q2 = *(const float4*)(&xsT[buf][ch][o + 8]);
            const float4 q3 = *(const float4*)(&xsT[buf][ch][o + 12]);
            a0 = fmaf(Preg[o + 0], q0.x, a0);  a0 = fmaf(Preg[o + 1], q0.y, a0);
            a0 = fmaf(Preg[o + 2], q0.z, a0);  a0 = fmaf(Preg[o + 3], q0.w, a0);
            a1 = fmaf(Preg[o + 4], q1.x, a1);  a1 = fmaf(Preg[o + 5], q1.y, a1);
            a1 = fmaf(Preg[o + 6], q1.z, a1);  a1 = fmaf(Preg[o + 7], q1.w, a1);
            a2 = fmaf(Preg[o + 8], q2.x, a2);  a2 = fmaf(Preg[o + 9], q2.y, a2);
            a2 = fmaf(Preg[o + 10], q2.z, a2); a2 = fmaf(Preg[o + 11], q2.w, a2);
            a3 = fmaf(Preg[o + 12], q3.x, a3); a3 = fmaf(Preg[o + 13], q3.y, a3);
            a3 = fmaf(Preg[o + 14], q3.z, a3); a3 = fmaf(Preg[o + 15], q3.w, a3);
        }
        const float c = (a0 + a1) + (a2 + a3);

        // hin_j = s_{j-1}; coalesced 1 KB per block
        hin[(((size_t)(b * NCH + j) * DMODEL) + d0) * 16 + t] = s;

        // s_j = A^64 s_{j-1} + c — 2 independent shfl-FMA chains
        float u0 = 0.0f, u1 = 0.0f;
        #pragma unroll
        for (int k = 0; k < 8; ++k) {
            u0 = fmaf(Arow[k],     __shfl(s, laneBase + k, 64),     u0);
            u1 = fmaf(Arow[k + 8], __shfl(s, laneBase + k + 8, 64), u1);
        }
        const float snew = c + (u0 + u1);

        __syncthreads();                   // single barrier per chunk
        s = snew;
        cur = nxt;
        buf ^= 1;
    }
}

// ---------------------------------------------------------------------------
// K3: identical to proven round-3/4 code EXCEPT __launch_bounds__(256, 4).
// (256,8) capped VGPRs at 64 vs the ~88 this kernel needs -> ~105 MB of
// scratch spill traffic. (256,4) gives a 128-VGPR budget; natural occupancy
// ~5 waves/EU, no spills.
//   y[tau] = W[tau].h_in + sum_{s<=tau} kv[tau-s] x[s]
// ---------------------------------------------------------------------------
template <int TT>
__device__ __forceinline__ void k3_body(const float* __restrict__ xs,
                                        const float* __restrict__ ws,
                                        float* __restrict__ y,
                                        int b, int j, int d, int dl) {
    const float* hinp = ws + WS_HIN + (((size_t)(b * NCH + j) * DMODEL) + d) * 16;
    float4 hv[4];
    #pragma unroll
    for (int q = 0; q < 4; ++q) hv[q] = ((const float4*)hinp)[q];

    float h[16];
    #pragma unroll
    for (int q = 0; q < 4; ++q) {
        h[4 * q]     = hv[q].x; h[4 * q + 1] = hv[q].y;
        h[4 * q + 2] = hv[q].z; h[4 * q + 3] = hv[q].w;
    }

    const float* W = ws + WS_W + TT * 16 * 16;
    float yv[16];
    #pragma unroll
    for (int i = 0; i < 16; ++i) {
        float acc = 0.0f;
        #pragma unroll
        for (int m = 0; m < 16; ++m) acc = fmaf(W[i * 16 + m], h[m], acc);
        yv[i] = acc;
    }

    __syncthreads();                      // xs tile ready

    const float* kv63 = ws + WS_KV + 63;  // kv63[q] = B^T A^q B
    #pragma unroll
    for (int ss = 0; ss < (TT + 1) * 16; ++ss) {
        const float xv = xs[ss * 64 + dl];
        #pragma unroll
        for (int i = 0; i < 16; ++i) {
            if (TT * 16 + i >= ss)
                yv[i] = fmaf(kv63[TT * 16 + i - ss], xv, yv[i]);
        }
    }

    float* yp = y + ((size_t)(b * SEQL + j * CT + TT * 16)) * DMODEL + d;
    #pragma unroll
    for (int i = 0; i < 16; ++i) yp[(size_t)i * DMODEL] = yv[i];
}

__global__ __launch_bounds__(256, 4) void k3_output(const float* __restrict__ x,
                                                    const float* __restrict__ ws,
                                                    float* __restrict__ y) {
    __shared__ __align__(16) float xs[CT * 64];    // [sigma][dl], 16 KiB
    const int blk  = blockIdx.x;          // 2048 blocks
    const int b    = blk >> 9;
    const int j    = (blk >> 4) & 31;
    const int dblk = blk & 15;
    const int t    = threadIdx.x;
    const int tq   = t >> 6;              // tau quarter = wave index
    const int dl   = t & 63;
    const int d    = dblk * 64 + dl;

    {
        const float* xp = x + ((size_t)(b * SEQL + j * CT)) * DMODEL + dblk * 64;
        #pragma unroll
        for (int k = 0; k < 4; ++k) {
            const int f     = k * 256 + t;
            const int sigma = f >> 4;
            const int cc    = f & 15;
            *(float4*)(&xs[sigma * 64 + cc * 4]) =
                *(const float4*)(xp + (size_t)sigma * DMODEL + cc * 4);
        }
    }

    switch (tq) {                          // wave-uniform branch
        case 0: k3_body<0>(xs, ws, y, b, j, d, dl); break;
        case 1: k3_body<1>(xs, ws, y, b, j, d, dl); break;
        case 2: k3_body<2>(xs, ws, y, b, j, d, dl); break;
        default: k3_body<3>(xs, ws, y, b, j, d, dl); break;
    }
}

// ---------------------------------------------------------------------------
extern "C" void kernel_launch(void* const* d_in, const int* in_sizes, int n_in,
                              void* d_out, int out_size, void* d_ws, size_t ws_size,
                              hipStream_t stream) {
    (void)in_sizes; (void)n_in; (void)out_size; (void)ws_size;
    const float* x  = (const float*)d_in[0];
    const float* A  = (const float*)d_in[1];
    const float* Bv = (const float*)d_in[2];
    float* out = (float*)d_out;
    float* ws  = (float*)d_ws;

    ka_tables_scan<<<256, 256, 0, stream>>>(x, A, Bv, ws);
    k3_output<<<2048, 256, 0, stream>>>(x, ws, out);
}